// Round 2
// baseline (330.956 us; speedup 1.0000x reference)
//
#include <hip/hip_runtime.h>
#include <hip/hip_bf16.h>
#include <stdint.h>

// All FLOAT32 I/O. bf16 compute via convert pre-pass; m97-style GLDS16 GEMMs;
// attn = R5-structure flash kernel, K-SPLIT x2 (fixed-base softmax => partials
// are plain sums; merged by a cheap elementwise kernel).
// v7: swapped QK^T (S^T in regs) + in-register softmax via cvt_pk_bf16_f32 +
// permlane{32,16}_swap redistribution. No Ps LDS buffer, no lgkmcnt drain,
// 1 mask word/lane/iter, Q pre-scaled by 0.125*log2(e) in qkv_gemm.
// v8: attn residency 6 -> 8 blocks/CU (grid is exactly 8/CU; full co-residency
// kills the 6+2 residency split + tail and hides per-iter load latency by TLP).
// pack_mask fused into cvt_all_k (blockIdx.y == 7) — one less dispatch.
#define SEQ     2048
#define NBATCH  2
#define DMODEL  1024
#define NH      16
#define DKH     64

typedef __bf16 bf16;
typedef __attribute__((ext_vector_type(8))) __bf16 bf16x8;
typedef __attribute__((ext_vector_type(4))) __bf16 bf16x4;
typedef __attribute__((ext_vector_type(4))) float  f32x4;

static __device__ __forceinline__ f32x4 mfma16(bf16x8 a, bf16x8 b, f32x4 c) {
    return __builtin_amdgcn_mfma_f32_16x16x32_bf16(a, b, c, 0, 0, 0);
}

// async global->LDS, 16B per lane, LDS dst = wave-uniform base + lane*16
typedef const __attribute__((address_space(1))) void* gas_cptr;
typedef __attribute__((address_space(3))) void*       las_ptr;
#define GLDS16(g, l) __builtin_amdgcn_global_load_lds((gas_cptr)(g), (las_ptr)(l), 16, 0, 0)

// in-place cross-lane row swaps (gfx950)
#define PL32SWAP(a, b) asm("v_permlane32_swap_b32 %0, %1" : "+v"(a), "+v"(b))
#define PL16SWAP(a, b) asm("v_permlane16_swap_b32 %0, %1" : "+v"(a), "+v"(b))

// ---------------------------------------------------------------------------
// Kernel 0: f32 -> bf16 convert for X (q,k,v) and W (wq,wk,wv,wo); y=7 packs
// mask [n,1,s,s] int32 -> bitmask uint64 [n*s, s/64].
// ---------------------------------------------------------------------------
__global__ __launch_bounds__(256) void cvt_all_k(const float* __restrict__ q,
                                                 const float* __restrict__ k,
                                                 const float* __restrict__ v,
                                                 const float* __restrict__ wq,
                                                 const float* __restrict__ wk,
                                                 const float* __restrict__ wv,
                                                 const float* __restrict__ wo,
                                                 const int* __restrict__ mask,
                                                 bf16* __restrict__ qb, bf16* __restrict__ kb,
                                                 bf16* __restrict__ vb, bf16* __restrict__ wqb,
                                                 bf16* __restrict__ wkb, bf16* __restrict__ wvb,
                                                 bf16* __restrict__ wob,
                                                 unsigned long long* __restrict__ mbits) {
    if (blockIdx.y == 7) {  // mask pack
        const int nwords = NBATCH * SEQ * (SEQ / 64);
        int wave  = (blockIdx.x * blockDim.x + threadIdx.x) >> 6;
        int lane  = threadIdx.x & 63;
        int nwtot = (gridDim.x * blockDim.x) >> 6;
        for (int w = wave; w < nwords; w += nwtot) {
            int m = mask[(size_t)w * 64 + lane];
            unsigned long long b = __ballot(m != 0);
            if (lane == 0) mbits[w] = b;
        }
        return;
    }
    const float* src; bf16* dst; int n4;
    const int NX4 = (NBATCH * SEQ * DMODEL) / 4, NW4 = (DMODEL * DMODEL) / 4;
    switch (blockIdx.y) {
        case 0: src = q;  dst = qb;  n4 = NX4; break;
        case 1: src = k;  dst = kb;  n4 = NX4; break;
        case 2: src = v;  dst = vb;  n4 = NX4; break;
        case 3: src = wq; dst = wqb; n4 = NW4; break;
        case 4: src = wk; dst = wkb; n4 = NW4; break;
        case 5: src = wv; dst = wvb; n4 = NW4; break;
        default: src = wo; dst = wob; n4 = NW4; break;
    }
    int stride = gridDim.x * blockDim.x;
    for (int i = blockIdx.x * blockDim.x + threadIdx.x; i < n4; i += stride) {
        f32x4 f = ((const f32x4*)src)[i];
        bf16x4 o;
#pragma unroll
        for (int j = 0; j < 4; j++) o[j] = (bf16)f[j];
        ((bf16x4*)dst)[i] = o;
    }
}

// ---------------------------------------------------------------------------
// Kernel 2: QKV projection, m97-style GLDS16 staging, unpadded 128x32 tiles.
// z=0:Q (pre-scaled by 0.125*log2e) z=1:K -> [n,h,s,64]; z=2:V -> [n,h,64,s].
// ---------------------------------------------------------------------------
__global__ __launch_bounds__(256) void qkv_gemm(const bf16* __restrict__ Xq,
                                                const bf16* __restrict__ Xk,
                                                const bf16* __restrict__ Xv,
                                                const bf16* __restrict__ Wq,
                                                const bf16* __restrict__ Wk,
                                                const bf16* __restrict__ Wv,
                                                bf16* __restrict__ Qo,
                                                bf16* __restrict__ Ko,
                                                bf16* __restrict__ Vto) {
    __shared__ bf16 As[128 * 32], Bs[128 * 32];
    const int z = blockIdx.z;
    const bf16* A = (z == 0) ? Xq : (z == 1) ? Xk : Xv;
    const bf16* W = (z == 0) ? Wq : (z == 1) ? Wk : Wv;
    const int bm = blockIdx.x * 128, bn = blockIdx.y * 128;
    const int tid = threadIdx.x, wave = tid >> 6, lane = tid & 63;
    const int wm = wave >> 1, wn = wave & 1, lo = lane & 15, hi = lane >> 4;

    const int r0 = wave * 32 + (lane >> 2);
    const int c8 = (lane & 3) * 8;
    const bf16* Ag = A + (size_t)(bm + r0) * DMODEL + c8;
    const bf16* Bg = W + (size_t)(bn + r0) * DMODEL + c8;
    bf16* lA = &As[wave * 1024];
    bf16* lB = &Bs[wave * 1024];

    f32x4 acc[4][4];
#pragma unroll
    for (int i = 0; i < 4; i++)
#pragma unroll
        for (int j = 0; j < 4; j++) acc[i][j] = 0.0f;

    for (int k0 = 0; k0 < DMODEL; k0 += 32) {
        __syncthreads();
        GLDS16(Ag + k0, lA);
        GLDS16(Ag + k0 + (size_t)16 * DMODEL, lA + 512);
        GLDS16(Bg + k0, lB);
        GLDS16(Bg + k0 + (size_t)16 * DMODEL, lB + 512);
        __syncthreads();

        bf16x8 a[4], b[4];
#pragma unroll
        for (int t = 0; t < 4; t++) {
            a[t] = *(const bf16x8*)&As[(wm * 64 + t * 16 + lo) * 32 + hi * 8];
            b[t] = *(const bf16x8*)&Bs[(wn * 64 + t * 16 + lo) * 32 + hi * 8];
        }
#pragma unroll
        for (int tm = 0; tm < 4; tm++)
#pragma unroll
            for (int tn = 0; tn < 4; tn++)
                acc[tm][tn] = mfma16(a[tm], b[tn], acc[tm][tn]);
    }

    if (z < 2) {
        bf16* O = (z == 0) ? Qo : Ko;
        const float qscale = (z == 0) ? 0.18033688f : 1.0f;  // 0.125 * log2(e)
#pragma unroll
        for (int tm = 0; tm < 4; tm++)
#pragma unroll
            for (int tn = 0; tn < 4; tn++)
#pragma unroll
                for (int r = 0; r < 4; r++) {
                    int m = bm + wm * 64 + tm * 16 + hi * 4 + r;
                    int o = bn + wn * 64 + tn * 16 + lo;
                    int nidx = m >> 11, sq = m & 2047;
                    int hh = o >> 6, d = o & 63;
                    O[(((size_t)nidx * NH + hh) * SEQ + sq) * DKH + d] = (bf16)(acc[tm][tn][r] * qscale);
                }
    } else {
#pragma unroll
        for (int tm = 0; tm < 4; tm++)
#pragma unroll
            for (int tn = 0; tn < 4; tn++)
#pragma unroll
                for (int r = 0; r < 4; r++) {
                    int m = bm + wm * 64 + tm * 16 + hi * 4 + r;
                    int o = bn + wn * 64 + tn * 16 + lo;
                    int nidx = m >> 11, sq = m & 2047;
                    int hh = o >> 6, d = o & 63;
                    Vto[(((size_t)nidx * NH + hh) * DKH + d) * SEQ + sq] = (bf16)acc[tm][tn][r];
                }
    }
}

// ---------------------------------------------------------------------------
// Kernel 3: flash attention v8 — swapped QK^T (S^T: lane holds P[q=lo][16 k's])
// + in-register P->bf16 fragment build (cvt_pk + permlane32/16_swap). No Ps
// buffer (LDS 18.4 KB), no intra-iter LDS round trip. K-SPLIT x2.
// Residency 8 blocks/CU: grid 2048 = exactly 8/CU, all blocks co-resident;
// per-iter load latency hidden by 8-way TLP (VGPR 40 <= 64 so no spill).
// ---------------------------------------------------------------------------
__global__ __launch_bounds__(256, 8) void attn_k(const bf16* __restrict__ Q,
                                                 const bf16* __restrict__ K,
                                                 const bf16* __restrict__ Vt,
                                                 const unsigned long long* __restrict__ mbits,
                                                 bf16* __restrict__ Op0,
                                                 bf16* __restrict__ Op1,
                                                 float* __restrict__ Lp) {
    __shared__ bf16 Ks[64 * 72];
    __shared__ bf16 Vs[64 * 72];

    const int bid = blockIdx.x;
    const int xcd = bid & 7, j = bid >> 3;        // j: 0..255
    const int hd = xcd * 4 + (j & 3);             // head index 0..31 (= n*16+h)
    const int qb = (j >> 2) & 31;                 // q-block 0..31
    const int ks = j >> 7;                        // k-half 0..1
    const int n = hd >> 4, h = hd & 15;

    const int tid = threadIdx.x, wave = tid >> 6, lane = tid & 63;
    const int lo = lane & 15, hi = lane >> 4;

    const size_t headoff = (size_t)hd * SEQ * DKH;
    const bf16* Qh = Q + headoff;
    const bf16* Kh = K + headoff;
    const bf16* Vh = Vt + headoff;   // [64][2048]

    const int qrow = qb * 64 + wave * 16 + lo;
    const bf16x8 aq0 = *(const bf16x8*)(Qh + (size_t)qrow * DKH + hi * 8);
    const bf16x8 aq1 = *(const bf16x8*)(Qh + (size_t)qrow * DKH + 32 + hi * 8);

    bf16x8 ones;
#pragma unroll
    for (int i = 0; i < 8; i++) ones[i] = (bf16)1.0f;

    f32x4 oacc[4];
#pragma unroll
    for (int t = 0; t < 4; t++) oacc[t] = 0.0f;
    f32x4 lacc; lacc = 0.0f;

    // per-lane mask row: q-row = qrow, one 64-bit word per 64-k tile
    const unsigned long long* mbq = mbits + ((size_t)n * SEQ + qrow) * (SEQ / 64);

    const int kbeg = ks * 1024, kend = kbeg + 1024;

    const int srow = tid >> 3, sseg = tid & 7;   // 32 rows x 64 cols per store round
    const bf16* Kg = Kh + (size_t)srow * DKH + sseg * 8;
    const bf16* Vg = Vh + (size_t)srow * SEQ + sseg * 8;

    // preload first tile of this k-half into registers
    bf16x8 rk0 = *(const bf16x8*)(Kg + (size_t)kbeg * DKH);
    bf16x8 rk1 = *(const bf16x8*)(Kg + (size_t)(kbeg + 32) * DKH);
    bf16x8 rv0 = *(const bf16x8*)(Vg + kbeg);
    bf16x8 rv1 = *(const bf16x8*)(Vg + (size_t)32 * SEQ + kbeg);
    unsigned long long wm = mbq[kbeg >> 6];
    unsigned long long wmn = 0;

#pragma unroll 1
    for (int k0 = kbeg; k0 < kend; k0 += 64) {
        __syncthreads();
        *(bf16x8*)&Ks[srow * 72 + sseg * 8]        = rk0;
        *(bf16x8*)&Ks[(srow + 32) * 72 + sseg * 8] = rk1;
        *(bf16x8*)&Vs[srow * 72 + sseg * 8]        = rv0;
        *(bf16x8*)&Vs[(srow + 32) * 72 + sseg * 8] = rv1;
        if (k0 + 64 < kend) {  // prefetch next tile (overlaps compute below)
            rk0 = *(const bf16x8*)(Kg + (size_t)(k0 + 64) * DKH);
            rk1 = *(const bf16x8*)(Kg + (size_t)(k0 + 96) * DKH);
            rv0 = *(const bf16x8*)(Vg + k0 + 64);
            rv1 = *(const bf16x8*)(Vg + (size_t)32 * SEQ + k0 + 64);
            wmn = mbq[(k0 >> 6) + 1];
        }
        __syncthreads();

        // S^T = K Q^T : lane (lo,hi) gets S[k=tn*16+hi*4+r][q=lo] (Q pre-scaled)
        // then p = exp2(s), masked -> 0, packed to bf16 pairs.
        unsigned wlo = (unsigned)(wm >> (hi * 4));
        unsigned whi = (unsigned)(wm >> (hi * 4 + 32));
        uint32_t pk[4][2];
#pragma unroll
        for (int tn = 0; tn < 4; tn++) {
            const int kr = (tn * 16 + lo) * 72;
            bf16x8 b0 = *(const bf16x8*)&Ks[kr + hi * 8];
            bf16x8 b1 = *(const bf16x8*)&Ks[kr + 32 + hi * 8];
            f32x4 z4; z4 = 0.0f;
            z4 = mfma16(b0, aq0, z4);
            z4 = mfma16(b1, aq1, z4);
            unsigned ws = ((tn < 2) ? wlo : whi) >> ((tn & 1) * 16);
            float pv[4];
#pragma unroll
            for (int r = 0; r < 4; r++) {
                float e = __builtin_amdgcn_exp2f(z4[r]);
                pv[r] = ((ws >> r) & 1u) ? e : 0.0f;
            }
            asm("v_cvt_pk_bf16_f32 %0, %1, %2" : "=v"(pk[tn][0]) : "v"(pv[0]), "v"(pv[1]));
            asm("v_cvt_pk_bf16_f32 %0, %1, %2" : "=v"(pk[tn][1]) : "v"(pv[2]), "v"(pv[3]));
        }
        wm = wmn;

        // Redistribute across hi-groups: lane needs P[q=lo][k=K32*32+hi*8+j].
        // For x=pk[t][u], y=pk[t+1][u]: PL32;PL16 -> x=[x@0,x@2,y@0,y@2] (d0),
        // y=[x@1,x@3,y@1,y@3] (d2) indexed by hi.
        uint32_t d00 = pk[0][0], d02 = pk[1][0];
        PL32SWAP(d00, d02); PL16SWAP(d00, d02);
        uint32_t d01 = pk[0][1], d03 = pk[1][1];
        PL32SWAP(d01, d03); PL16SWAP(d01, d03);
        uint32_t d10 = pk[2][0], d12 = pk[3][0];
        PL32SWAP(d10, d12); PL16SWAP(d10, d12);
        uint32_t d11 = pk[2][1], d13 = pk[3][1];
        PL32SWAP(d11, d13); PL16SWAP(d11, d13);

        union FragU { uint32_t u[4]; bf16x8 v; };
        FragU f0, f1;
        f0.u[0] = d00; f0.u[1] = d01; f0.u[2] = d02; f0.u[3] = d03;
        f1.u[0] = d10; f1.u[1] = d11; f1.u[2] = d12; f1.u[3] = d13;
        bf16x8 ap0 = f0.v;   // k 0..31 of this tile
        bf16x8 ap1 = f1.v;   // k 32..63

#pragma unroll
        for (int td = 0; td < 4; td++) {
            bf16x8 b0 = *(const bf16x8*)&Vs[(td * 16 + lo) * 72 + hi * 8];
            bf16x8 b1 = *(const bf16x8*)&Vs[(td * 16 + lo) * 72 + 32 + hi * 8];
            oacc[td] = mfma16(ap0, b0, oacc[td]);
            oacc[td] = mfma16(ap1, b1, oacc[td]);
        }
        lacc = mfma16(ap0, ones, lacc);
        lacc = mfma16(ap1, ones, lacc);
    }

    // epilogue: write bf16 partial O [n,q,h*64+d] and f32 partial l [ks][n,h,q]
    bf16* Op = ks ? Op1 : Op0;
#pragma unroll
    for (int td = 0; td < 4; td++)
#pragma unroll
        for (int r = 0; r < 4; r++) {
            int q = qb * 64 + wave * 16 + hi * 4 + r;
            int d = td * 16 + lo;
            Op[((size_t)n * SEQ + q) * DMODEL + h * 64 + d] = (bf16)oacc[td][r];
        }
    if (lo == 0) {
#pragma unroll
        for (int r = 0; r < 4; r++) {
            int q = qb * 64 + wave * 16 + hi * 4 + r;
            Lp[(size_t)ks * (NBATCH * NH * SEQ) + ((size_t)(n * NH + h) * SEQ) + q] = lacc[r];
        }
    }
}

// ---------------------------------------------------------------------------
// Kernel 3b: merge partials: A = (o0 + o1) / (l0 + l1), bf16 out. HBM-bound.
// ---------------------------------------------------------------------------
__global__ __launch_bounds__(256) void merge_k(const bf16* __restrict__ o0,
                                               const bf16* __restrict__ o1,
                                               const float* __restrict__ lp,
                                               bf16* __restrict__ Aout) {
    int t = blockIdx.x * blockDim.x + threadIdx.x;   // 0 .. 4096*128-1 (8 elems each)
    int q = t >> 7;                                  // n*SEQ + s
    int h = (t >> 3) & 15;                           // (t&127)*8 >> 6
    int n = q >> 11;
    bf16x8 a = ((const bf16x8*)o0)[t];
    bf16x8 b = ((const bf16x8*)o1)[t];
    int li = (n * NH + h) * SEQ + (q & 2047);
    float l = lp[li] + lp[NBATCH * NH * SEQ + li];
    float rl = 1.0f / l;
    bf16x8 o;
#pragma unroll
    for (int i = 0; i < 8; i++) o[i] = (bf16)(((float)a[i] + (float)b[i]) * rl);
    ((bf16x8*)Aout)[t] = o;
}

// ---------------------------------------------------------------------------
// Kernel 4: out = Attn(bf16) @ Wo(bf16)^T + bo, FP32 out. m97-style staging.
// ---------------------------------------------------------------------------
__global__ __launch_bounds__(256) void out_gemm(const bf16* __restrict__ A,
                                                const bf16* __restrict__ W,
                                                const float* __restrict__ bias,
                                                float* __restrict__ Out) {
    __shared__ bf16 As[128 * 32], Bs[128 * 32];
    const int bm = blockIdx.x * 128, bn = blockIdx.y * 128;
    const int tid = threadIdx.x, wave = tid >> 6, lane = tid & 63;
    const int wm = wave >> 1, wn = wave & 1, lo = lane & 15, hi = lane >> 4;

    const int r0 = wave * 32 + (lane >> 2);
    const int c8 = (lane & 3) * 8;
    const bf16* Ag = A + (size_t)(bm + r0) * DMODEL + c8;
    const bf16* Bg = W + (size_t)(bn + r0) * DMODEL + c8;
    bf16* lA = &As[wave * 1024];
    bf16* lB = &Bs[wave * 1024];

    f32x4 acc[4][4];
#pragma unroll
    for (int i = 0; i < 4; i++)
#pragma unroll
        for (int j = 0; j < 4; j++) acc[i][j] = 0.0f;

    for (int k0 = 0; k0 < DMODEL; k0 += 32) {
        __syncthreads();
        GLDS16(Ag + k0, lA);
        GLDS16(Ag + k0 + (size_t)16 * DMODEL, lA + 512);
        GLDS16(Bg + k0, lB);
        GLDS16(Bg + k0 + (size_t)16 * DMODEL, lB + 512);
        __syncthreads();

        bf16x8 a[4], b[4];
#pragma unroll
        for (int t = 0; t < 4; t++) {
            a[t] = *(const bf16x8*)&As[(wm * 64 + t * 16 + lo) * 32 + hi * 8];
            b[t] = *(const bf16x8*)&Bs[(wn * 64 + t * 16 + lo) * 32 + hi * 8];
        }
#pragma unroll
        for (int tm = 0; tm < 4; tm++)
#pragma unroll
            for (int tn = 0; tn < 4; tn++)
                acc[tm][tn] = mfma16(a[tm], b[tn], acc[tm][tn]);
    }

#pragma unroll
    for (int tm = 0; tm < 4; tm++)
#pragma unroll
        for (int tn = 0; tn < 4; tn++) {
            int o = bn + wn * 64 + tn * 16 + lo;
            float bv = bias[o];
#pragma unroll
            for (int r = 0; r < 4; r++) {
                int m = bm + wm * 64 + tm * 16 + hi * 4 + r;
                Out[(size_t)m * DMODEL + o] = acc[tm][tn][r] + bv;
            }
        }
}

// ---------------------------------------------------------------------------
extern "C" void kernel_launch(void* const* d_in, const int* in_sizes, int n_in,
                              void* d_out, int out_size, void* d_ws, size_t ws_size,
                              hipStream_t stream) {
    const float* value = (const float*)d_in[0];
    const float* key   = (const float*)d_in[1];
    const float* query = (const float*)d_in[2];
    const int*   mask  = (const int*)d_in[3];
    const float* Wq    = (const float*)d_in[4];
    const float* Wk    = (const float*)d_in[5];
    const float* Wv    = (const float*)d_in[6];
    const float* Wo    = (const float*)d_in[7];
    const float* bo    = (const float*)d_in[8];
    float* out = (float*)d_out;

    char* ws = (char*)d_ws;
    bf16* Qws = (bf16*)(ws);                         // 8 MB [n,h,s,64]
    bf16* Kws = (bf16*)(ws + (8u  << 20));           // 8 MB [n,h,s,64]
    bf16* Vt  = (bf16*)(ws + (16u << 20));           // 8 MB [n,h,64,s]
    bf16* Xqb = (bf16*)(ws + (24u << 20));           // 8 MB; after qkv: o_part0
    bf16* Xkb = (bf16*)(ws + (32u << 20));           // 8 MB; after qkv: o_part1
    bf16* Xvb = (bf16*)(ws + (40u << 20));           // 8 MB; after qkv: Aws (merged)
    bf16* Wqb = (bf16*)(ws + (48u << 20));           // 2 MB; after qkv: l_part (512KB)
    bf16* Wkb = (bf16*)(ws + (50u << 20));           // 2 MB
    bf16* Wvb = (bf16*)(ws + (52u << 20));           // 2 MB
    bf16* Wob = (bf16*)(ws + (54u << 20));           // 2 MB (live until out_gemm)
    unsigned long long* mbits = (unsigned long long*)(ws + (56u << 20));  // 1 MB
    bf16*  Op0 = Xqb;
    bf16*  Op1 = Xkb;
    bf16*  Aws = Xvb;
    float* Lp  = (float*)Wqb;

    cvt_all_k<<<dim3(1024, 8), 256, 0, stream>>>(query, key, value, Wq, Wk, Wv, Wo, mask,
                                                 Xqb, Xkb, Xvb, Wqb, Wkb, Wvb, Wob, mbits);
    qkv_gemm<<<dim3(32, 8, 3), 256, 0, stream>>>(Xqb, Xkb, Xvb, Wqb, Wkb, Wvb, Qws, Kws, Vt);
    attn_k<<<2048, 256, 0, stream>>>(Qws, Kws, Vt, mbits, Op0, Op1, Lp);
    merge_k<<<2048, 256, 0, stream>>>(Op0, Op1, Lp, Aws);
    out_gemm<<<dim3(32, 8), 256, 0, stream>>>(Aws, Wob, bo, out);
}

// Round 3
// 272.590 us; speedup vs baseline: 1.2141x; 1.2141x over previous
//
#include <hip/hip_runtime.h>
#include <hip/hip_bf16.h>
#include <stdint.h>

// All FLOAT32 I/O. bf16 compute via convert pre-pass; m97-style GLDS16 GEMMs;
// attn = flash kernel, K-SPLIT x2 (fixed-base softmax => partials are plain
// sums; merged by a cheap elementwise kernel).
// v7: swapped QK^T (S^T in regs) + in-register softmax via cvt_pk_bf16_f32 +
// permlane{32,16}_swap redistribution.
// v8 (FAILED): launch_bounds(256,8) caused scratch spills (WRITE_SIZE 17->195MB).
// v9: attn is LDS-BW-bound (each wave reads whole K/V tile per iter: 47us of
// LDS-pipe time vs 66us dur). QBLK 64->128: 2 q-subtiles per wave reuse each
// K/V fragment read for 2 MFMAs -> LDS read traffic per FLOP halves.
// Grid 1024 = 4 blocks/CU; launch_bounds(256,4) caps VGPR at 128 (~110 needed,
// no spill). pack_mask stays fused into cvt_all_k.
#define SEQ     2048
#define NBATCH  2
#define DMODEL  1024
#define NH      16
#define DKH     64

typedef __bf16 bf16;
typedef __attribute__((ext_vector_type(8))) __bf16 bf16x8;
typedef __attribute__((ext_vector_type(4))) __bf16 bf16x4;
typedef __attribute__((ext_vector_type(4))) float  f32x4;

static __device__ __forceinline__ f32x4 mfma16(bf16x8 a, bf16x8 b, f32x4 c) {
    return __builtin_amdgcn_mfma_f32_16x16x32_bf16(a, b, c, 0, 0, 0);
}

// async global->LDS, 16B per lane, LDS dst = wave-uniform base + lane*16
typedef const __attribute__((address_space(1))) void* gas_cptr;
typedef __attribute__((address_space(3))) void*       las_ptr;
#define GLDS16(g, l) __builtin_amdgcn_global_load_lds((gas_cptr)(g), (las_ptr)(l), 16, 0, 0)

// in-place cross-lane row swaps (gfx950)
#define PL32SWAP(a, b) asm("v_permlane32_swap_b32 %0, %1" : "+v"(a), "+v"(b))
#define PL16SWAP(a, b) asm("v_permlane16_swap_b32 %0, %1" : "+v"(a), "+v"(b))

// ---------------------------------------------------------------------------
// Kernel 0: f32 -> bf16 convert for X (q,k,v) and W (wq,wk,wv,wo); y=7 packs
// mask [n,1,s,s] int32 -> bitmask uint64 [n*s, s/64].
// ---------------------------------------------------------------------------
__global__ __launch_bounds__(256) void cvt_all_k(const float* __restrict__ q,
                                                 const float* __restrict__ k,
                                                 const float* __restrict__ v,
                                                 const float* __restrict__ wq,
                                                 const float* __restrict__ wk,
                                                 const float* __restrict__ wv,
                                                 const float* __restrict__ wo,
                                                 const int* __restrict__ mask,
                                                 bf16* __restrict__ qb, bf16* __restrict__ kb,
                                                 bf16* __restrict__ vb, bf16* __restrict__ wqb,
                                                 bf16* __restrict__ wkb, bf16* __restrict__ wvb,
                                                 bf16* __restrict__ wob,
                                                 unsigned long long* __restrict__ mbits) {
    if (blockIdx.y == 7) {  // mask pack
        const int nwords = NBATCH * SEQ * (SEQ / 64);
        int wave  = (blockIdx.x * blockDim.x + threadIdx.x) >> 6;
        int lane  = threadIdx.x & 63;
        int nwtot = (gridDim.x * blockDim.x) >> 6;
        for (int w = wave; w < nwords; w += nwtot) {
            int m = mask[(size_t)w * 64 + lane];
            unsigned long long b = __ballot(m != 0);
            if (lane == 0) mbits[w] = b;
        }
        return;
    }
    const float* src; bf16* dst; int n4;
    const int NX4 = (NBATCH * SEQ * DMODEL) / 4, NW4 = (DMODEL * DMODEL) / 4;
    switch (blockIdx.y) {
        case 0: src = q;  dst = qb;  n4 = NX4; break;
        case 1: src = k;  dst = kb;  n4 = NX4; break;
        case 2: src = v;  dst = vb;  n4 = NX4; break;
        case 3: src = wq; dst = wqb; n4 = NW4; break;
        case 4: src = wk; dst = wkb; n4 = NW4; break;
        case 5: src = wv; dst = wvb; n4 = NW4; break;
        default: src = wo; dst = wob; n4 = NW4; break;
    }
    int stride = gridDim.x * blockDim.x;
    for (int i = blockIdx.x * blockDim.x + threadIdx.x; i < n4; i += stride) {
        f32x4 f = ((const f32x4*)src)[i];
        bf16x4 o;
#pragma unroll
        for (int j = 0; j < 4; j++) o[j] = (bf16)f[j];
        ((bf16x4*)dst)[i] = o;
    }
}

// ---------------------------------------------------------------------------
// Kernel 2: QKV projection, m97-style GLDS16 staging, unpadded 128x32 tiles.
// z=0:Q (pre-scaled by 0.125*log2e) z=1:K -> [n,h,s,64]; z=2:V -> [n,h,64,s].
// ---------------------------------------------------------------------------
__global__ __launch_bounds__(256) void qkv_gemm(const bf16* __restrict__ Xq,
                                                const bf16* __restrict__ Xk,
                                                const bf16* __restrict__ Xv,
                                                const bf16* __restrict__ Wq,
                                                const bf16* __restrict__ Wk,
                                                const bf16* __restrict__ Wv,
                                                bf16* __restrict__ Qo,
                                                bf16* __restrict__ Ko,
                                                bf16* __restrict__ Vto) {
    __shared__ bf16 As[128 * 32], Bs[128 * 32];
    const int z = blockIdx.z;
    const bf16* A = (z == 0) ? Xq : (z == 1) ? Xk : Xv;
    const bf16* W = (z == 0) ? Wq : (z == 1) ? Wk : Wv;
    const int bm = blockIdx.x * 128, bn = blockIdx.y * 128;
    const int tid = threadIdx.x, wave = tid >> 6, lane = tid & 63;
    const int wm = wave >> 1, wn = wave & 1, lo = lane & 15, hi = lane >> 4;

    const int r0 = wave * 32 + (lane >> 2);
    const int c8 = (lane & 3) * 8;
    const bf16* Ag = A + (size_t)(bm + r0) * DMODEL + c8;
    const bf16* Bg = W + (size_t)(bn + r0) * DMODEL + c8;
    bf16* lA = &As[wave * 1024];
    bf16* lB = &Bs[wave * 1024];

    f32x4 acc[4][4];
#pragma unroll
    for (int i = 0; i < 4; i++)
#pragma unroll
        for (int j = 0; j < 4; j++) acc[i][j] = 0.0f;

    for (int k0 = 0; k0 < DMODEL; k0 += 32) {
        __syncthreads();
        GLDS16(Ag + k0, lA);
        GLDS16(Ag + k0 + (size_t)16 * DMODEL, lA + 512);
        GLDS16(Bg + k0, lB);
        GLDS16(Bg + k0 + (size_t)16 * DMODEL, lB + 512);
        __syncthreads();

        bf16x8 a[4], b[4];
#pragma unroll
        for (int t = 0; t < 4; t++) {
            a[t] = *(const bf16x8*)&As[(wm * 64 + t * 16 + lo) * 32 + hi * 8];
            b[t] = *(const bf16x8*)&Bs[(wn * 64 + t * 16 + lo) * 32 + hi * 8];
        }
#pragma unroll
        for (int tm = 0; tm < 4; tm++)
#pragma unroll
            for (int tn = 0; tn < 4; tn++)
                acc[tm][tn] = mfma16(a[tm], b[tn], acc[tm][tn]);
    }

    if (z < 2) {
        bf16* O = (z == 0) ? Qo : Ko;
        const float qscale = (z == 0) ? 0.18033688f : 1.0f;  // 0.125 * log2(e)
#pragma unroll
        for (int tm = 0; tm < 4; tm++)
#pragma unroll
            for (int tn = 0; tn < 4; tn++)
#pragma unroll
                for (int r = 0; r < 4; r++) {
                    int m = bm + wm * 64 + tm * 16 + hi * 4 + r;
                    int o = bn + wn * 64 + tn * 16 + lo;
                    int nidx = m >> 11, sq = m & 2047;
                    int hh = o >> 6, d = o & 63;
                    O[(((size_t)nidx * NH + hh) * SEQ + sq) * DKH + d] = (bf16)(acc[tm][tn][r] * qscale);
                }
    } else {
#pragma unroll
        for (int tm = 0; tm < 4; tm++)
#pragma unroll
            for (int tn = 0; tn < 4; tn++)
#pragma unroll
                for (int r = 0; r < 4; r++) {
                    int m = bm + wm * 64 + tm * 16 + hi * 4 + r;
                    int o = bn + wn * 64 + tn * 16 + lo;
                    int nidx = m >> 11, sq = m & 2047;
                    int hh = o >> 6, d = o & 63;
                    Vto[(((size_t)nidx * NH + hh) * DKH + d) * SEQ + sq] = (bf16)acc[tm][tn][r];
                }
    }
}

// ---------------------------------------------------------------------------
// Kernel 3: flash attention v9 — QBLK=128: each wave owns TWO 16-row q-groups
// (rows +0 and +64); K/V fragment ds_reads are shared between the two
// q-subtiles (2 MFMAs per B-fragment read) -> LDS read traffic per FLOP
// halves vs v7. Swapped QK^T + in-register softmax as v7. K-SPLIT x2.
// Grid 1024 = 4 blocks/CU, 4 waves/SIMD; VGPR ~110 under the 128 cap (256,4).
// ---------------------------------------------------------------------------
__global__ __launch_bounds__(256, 4) void attn_k(const bf16* __restrict__ Q,
                                                 const bf16* __restrict__ K,
                                                 const bf16* __restrict__ Vt,
                                                 const unsigned long long* __restrict__ mbits,
                                                 bf16* __restrict__ Op0,
                                                 bf16* __restrict__ Op1,
                                                 float* __restrict__ Lp) {
    __shared__ bf16 Ks[64 * 72];
    __shared__ bf16 Vs[64 * 72];

    const int bid = blockIdx.x;
    const int xcd = bid & 7, j = bid >> 3;        // j: 0..127
    const int hd = xcd * 4 + (j & 3);             // head index 0..31 (= n*16+h)
    const int qb = (j >> 2) & 15;                 // q-block 0..15 (128 rows each)
    const int ks = j >> 6;                        // k-half 0..1
    const int n = hd >> 4, h = hd & 15;

    const int tid = threadIdx.x, wave = tid >> 6, lane = tid & 63;
    const int lo = lane & 15, hi = lane >> 4;

    const size_t headoff = (size_t)hd * SEQ * DKH;
    const bf16* Qh = Q + headoff;
    const bf16* Kh = K + headoff;
    const bf16* Vh = Vt + headoff;   // [64][2048]

    const int qrowA = qb * 128 + wave * 16 + lo;
    const int qrowB = qrowA + 64;
    const bf16x8 aq0A = *(const bf16x8*)(Qh + (size_t)qrowA * DKH + hi * 8);
    const bf16x8 aq1A = *(const bf16x8*)(Qh + (size_t)qrowA * DKH + 32 + hi * 8);
    const bf16x8 aq0B = *(const bf16x8*)(Qh + (size_t)qrowB * DKH + hi * 8);
    const bf16x8 aq1B = *(const bf16x8*)(Qh + (size_t)qrowB * DKH + 32 + hi * 8);

    bf16x8 ones;
#pragma unroll
    for (int i = 0; i < 8; i++) ones[i] = (bf16)1.0f;

    f32x4 oaccA[4], oaccB[4];
#pragma unroll
    for (int t = 0; t < 4; t++) { oaccA[t] = 0.0f; oaccB[t] = 0.0f; }
    f32x4 laccA; laccA = 0.0f;
    f32x4 laccB; laccB = 0.0f;

    // per-lane mask rows (q-row = lane's lo within each subtile)
    const unsigned long long* mbqA = mbits + ((size_t)n * SEQ + qrowA) * (SEQ / 64);
    const unsigned long long* mbqB = mbits + ((size_t)n * SEQ + qrowB) * (SEQ / 64);

    const int kbeg = ks * 1024, kend = kbeg + 1024;

    const int srow = tid >> 3, sseg = tid & 7;   // 32 rows x 64 cols per store round
    const bf16* Kg = Kh + (size_t)srow * DKH + sseg * 8;
    const bf16* Vg = Vh + (size_t)srow * SEQ + sseg * 8;

    // preload first tile of this k-half into registers
    bf16x8 rk0 = *(const bf16x8*)(Kg + (size_t)kbeg * DKH);
    bf16x8 rk1 = *(const bf16x8*)(Kg + (size_t)(kbeg + 32) * DKH);
    bf16x8 rv0 = *(const bf16x8*)(Vg + kbeg);
    bf16x8 rv1 = *(const bf16x8*)(Vg + (size_t)32 * SEQ + kbeg);
    unsigned long long wmA = mbqA[kbeg >> 6];
    unsigned long long wmB = mbqB[kbeg >> 6];
    unsigned long long wmnA = 0, wmnB = 0;

    union FragU { uint32_t u[4]; bf16x8 v; };

#pragma unroll 1
    for (int k0 = kbeg; k0 < kend; k0 += 64) {
        __syncthreads();
        *(bf16x8*)&Ks[srow * 72 + sseg * 8]        = rk0;
        *(bf16x8*)&Ks[(srow + 32) * 72 + sseg * 8] = rk1;
        *(bf16x8*)&Vs[srow * 72 + sseg * 8]        = rv0;
        *(bf16x8*)&Vs[(srow + 32) * 72 + sseg * 8] = rv1;
        if (k0 + 64 < kend) {  // prefetch next tile (overlaps compute below)
            rk0 = *(const bf16x8*)(Kg + (size_t)(k0 + 64) * DKH);
            rk1 = *(const bf16x8*)(Kg + (size_t)(k0 + 96) * DKH);
            rv0 = *(const bf16x8*)(Vg + k0 + 64);
            rv1 = *(const bf16x8*)(Vg + (size_t)32 * SEQ + k0 + 64);
            wmnA = mbqA[(k0 >> 6) + 1];
            wmnB = mbqB[(k0 >> 6) + 1];
        }
        __syncthreads();

        // S^T = K Q^T for both q-subtiles; K-fragments read ONCE, used twice.
        unsigned wloA = (unsigned)(wmA >> (hi * 4));
        unsigned whiA = (unsigned)(wmA >> (hi * 4 + 32));
        unsigned wloB = (unsigned)(wmB >> (hi * 4));
        unsigned whiB = (unsigned)(wmB >> (hi * 4 + 32));
        uint32_t pkA[4][2], pkB[4][2];
#pragma unroll
        for (int tn = 0; tn < 4; tn++) {
            const int kr = (tn * 16 + lo) * 72;
            bf16x8 b0 = *(const bf16x8*)&Ks[kr + hi * 8];
            bf16x8 b1 = *(const bf16x8*)&Ks[kr + 32 + hi * 8];
            f32x4 zA; zA = 0.0f;
            zA = mfma16(b0, aq0A, zA);
            zA = mfma16(b1, aq1A, zA);
            f32x4 zB; zB = 0.0f;
            zB = mfma16(b0, aq0B, zB);
            zB = mfma16(b1, aq1B, zB);
            unsigned wsA = ((tn < 2) ? wloA : whiA) >> ((tn & 1) * 16);
            unsigned wsB = ((tn < 2) ? wloB : whiB) >> ((tn & 1) * 16);
            float pvA[4], pvB[4];
#pragma unroll
            for (int r = 0; r < 4; r++) {
                float eA = __builtin_amdgcn_exp2f(zA[r]);
                pvA[r] = ((wsA >> r) & 1u) ? eA : 0.0f;
                float eB = __builtin_amdgcn_exp2f(zB[r]);
                pvB[r] = ((wsB >> r) & 1u) ? eB : 0.0f;
            }
            asm("v_cvt_pk_bf16_f32 %0, %1, %2" : "=v"(pkA[tn][0]) : "v"(pvA[0]), "v"(pvA[1]));
            asm("v_cvt_pk_bf16_f32 %0, %1, %2" : "=v"(pkA[tn][1]) : "v"(pvA[2]), "v"(pvA[3]));
            asm("v_cvt_pk_bf16_f32 %0, %1, %2" : "=v"(pkB[tn][0]) : "v"(pvB[0]), "v"(pvB[1]));
            asm("v_cvt_pk_bf16_f32 %0, %1, %2" : "=v"(pkB[tn][1]) : "v"(pvB[2]), "v"(pvB[3]));
        }
        wmA = wmnA;
        wmB = wmnB;

        // Redistribute across hi-groups (per sub): lane needs P[q=lo][k=..hi*8+j]
        bf16x8 ap0A, ap1A, ap0B, ap1B;
        {
            uint32_t d00 = pkA[0][0], d02 = pkA[1][0];
            PL32SWAP(d00, d02); PL16SWAP(d00, d02);
            uint32_t d01 = pkA[0][1], d03 = pkA[1][1];
            PL32SWAP(d01, d03); PL16SWAP(d01, d03);
            uint32_t d10 = pkA[2][0], d12 = pkA[3][0];
            PL32SWAP(d10, d12); PL16SWAP(d10, d12);
            uint32_t d11 = pkA[2][1], d13 = pkA[3][1];
            PL32SWAP(d11, d13); PL16SWAP(d11, d13);
            FragU f0, f1;
            f0.u[0] = d00; f0.u[1] = d01; f0.u[2] = d02; f0.u[3] = d03;
            f1.u[0] = d10; f1.u[1] = d11; f1.u[2] = d12; f1.u[3] = d13;
            ap0A = f0.v; ap1A = f1.v;
        }
        {
            uint32_t d00 = pkB[0][0], d02 = pkB[1][0];
            PL32SWAP(d00, d02); PL16SWAP(d00, d02);
            uint32_t d01 = pkB[0][1], d03 = pkB[1][1];
            PL32SWAP(d01, d03); PL16SWAP(d01, d03);
            uint32_t d10 = pkB[2][0], d12 = pkB[3][0];
            PL32SWAP(d10, d12); PL16SWAP(d10, d12);
            uint32_t d11 = pkB[2][1], d13 = pkB[3][1];
            PL32SWAP(d11, d13); PL16SWAP(d11, d13);
            FragU f0, f1;
            f0.u[0] = d00; f0.u[1] = d01; f0.u[2] = d02; f0.u[3] = d03;
            f1.u[0] = d10; f1.u[1] = d11; f1.u[2] = d12; f1.u[3] = d13;
            ap0B = f0.v; ap1B = f1.v;
        }

        // PV: V-fragments read ONCE, used for both q-subtiles.
#pragma unroll
        for (int td = 0; td < 4; td++) {
            bf16x8 b0 = *(const bf16x8*)&Vs[(td * 16 + lo) * 72 + hi * 8];
            bf16x8 b1 = *(const bf16x8*)&Vs[(td * 16 + lo) * 72 + 32 + hi * 8];
            oaccA[td] = mfma16(ap0A, b0, oaccA[td]);
            oaccA[td] = mfma16(ap1A, b1, oaccA[td]);
            oaccB[td] = mfma16(ap0B, b0, oaccB[td]);
            oaccB[td] = mfma16(ap1B, b1, oaccB[td]);
        }
        laccA = mfma16(ap0A, ones, laccA);
        laccA = mfma16(ap1A, ones, laccA);
        laccB = mfma16(ap0B, ones, laccB);
        laccB = mfma16(ap1B, ones, laccB);
    }

    // epilogue: write bf16 partial O [n,q,h*64+d] and f32 partial l [ks][n,h,q]
    bf16* Op = ks ? Op1 : Op0;
#pragma unroll
    for (int td = 0; td < 4; td++)
#pragma unroll
        for (int r = 0; r < 4; r++) {
            int qA = qb * 128 + wave * 16 + hi * 4 + r;
            int qB = qA + 64;
            int d = td * 16 + lo;
            Op[((size_t)n * SEQ + qA) * DMODEL + h * 64 + d] = (bf16)oaccA[td][r];
            Op[((size_t)n * SEQ + qB) * DMODEL + h * 64 + d] = (bf16)oaccB[td][r];
        }
    if (lo == 0) {
#pragma unroll
        for (int r = 0; r < 4; r++) {
            int qA = qb * 128 + wave * 16 + hi * 4 + r;
            int qB = qA + 64;
            size_t base = (size_t)ks * (NBATCH * NH * SEQ) + ((size_t)(n * NH + h) * SEQ);
            Lp[base + qA] = laccA[r];
            Lp[base + qB] = laccB[r];
        }
    }
}

// ---------------------------------------------------------------------------
// Kernel 3b: merge partials: A = (o0 + o1) / (l0 + l1), bf16 out. HBM-bound.
// ---------------------------------------------------------------------------
__global__ __launch_bounds__(256) void merge_k(const bf16* __restrict__ o0,
                                               const bf16* __restrict__ o1,
                                               const float* __restrict__ lp,
                                               bf16* __restrict__ Aout) {
    int t = blockIdx.x * blockDim.x + threadIdx.x;   // 0 .. 4096*128-1 (8 elems each)
    int q = t >> 7;                                  // n*SEQ + s
    int h = (t >> 3) & 15;                           // (t&127)*8 >> 6
    int n = q >> 11;
    bf16x8 a = ((const bf16x8*)o0)[t];
    bf16x8 b = ((const bf16x8*)o1)[t];
    int li = (n * NH + h) * SEQ + (q & 2047);
    float l = lp[li] + lp[NBATCH * NH * SEQ + li];
    float rl = 1.0f / l;
    bf16x8 o;
#pragma unroll
    for (int i = 0; i < 8; i++) o[i] = (bf16)(((float)a[i] + (float)b[i]) * rl);
    ((bf16x8*)Aout)[t] = o;
}

// ---------------------------------------------------------------------------
// Kernel 4: out = Attn(bf16) @ Wo(bf16)^T + bo, FP32 out. m97-style staging.
// ---------------------------------------------------------------------------
__global__ __launch_bounds__(256) void out_gemm(const bf16* __restrict__ A,
                                                const bf16* __restrict__ W,
                                                const float* __restrict__ bias,
                                                float* __restrict__ Out) {
    __shared__ bf16 As[128 * 32], Bs[128 * 32];
    const int bm = blockIdx.x * 128, bn = blockIdx.y * 128;
    const int tid = threadIdx.x, wave = tid >> 6, lane = tid & 63;
    const int wm = wave >> 1, wn = wave & 1, lo = lane & 15, hi = lane >> 4;

    const int r0 = wave * 32 + (lane >> 2);
    const int c8 = (lane & 3) * 8;
    const bf16* Ag = A + (size_t)(bm + r0) * DMODEL + c8;
    const bf16* Bg = W + (size_t)(bn + r0) * DMODEL + c8;
    bf16* lA = &As[wave * 1024];
    bf16* lB = &Bs[wave * 1024];

    f32x4 acc[4][4];
#pragma unroll
    for (int i = 0; i < 4; i++)
#pragma unroll
        for (int j = 0; j < 4; j++) acc[i][j] = 0.0f;

    for (int k0 = 0; k0 < DMODEL; k0 += 32) {
        __syncthreads();
        GLDS16(Ag + k0, lA);
        GLDS16(Ag + k0 + (size_t)16 * DMODEL, lA + 512);
        GLDS16(Bg + k0, lB);
        GLDS16(Bg + k0 + (size_t)16 * DMODEL, lB + 512);
        __syncthreads();

        bf16x8 a[4], b[4];
#pragma unroll
        for (int t = 0; t < 4; t++) {
            a[t] = *(const bf16x8*)&As[(wm * 64 + t * 16 + lo) * 32 + hi * 8];
            b[t] = *(const bf16x8*)&Bs[(wn * 64 + t * 16 + lo) * 32 + hi * 8];
        }
#pragma unroll
        for (int tm = 0; tm < 4; tm++)
#pragma unroll
            for (int tn = 0; tn < 4; tn++)
                acc[tm][tn] = mfma16(a[tm], b[tn], acc[tm][tn]);
    }

#pragma unroll
    for (int tm = 0; tm < 4; tm++)
#pragma unroll
        for (int tn = 0; tn < 4; tn++) {
            int o = bn + wn * 64 + tn * 16 + lo;
            float bv = bias[o];
#pragma unroll
            for (int r = 0; r < 4; r++) {
                int m = bm + wm * 64 + tm * 16 + hi * 4 + r;
                Out[(size_t)m * DMODEL + o] = acc[tm][tn][r] + bv;
            }
        }
}

// ---------------------------------------------------------------------------
extern "C" void kernel_launch(void* const* d_in, const int* in_sizes, int n_in,
                              void* d_out, int out_size, void* d_ws, size_t ws_size,
                              hipStream_t stream) {
    const float* value = (const float*)d_in[0];
    const float* key   = (const float*)d_in[1];
    const float* query = (const float*)d_in[2];
    const int*   mask  = (const int*)d_in[3];
    const float* Wq    = (const float*)d_in[4];
    const float* Wk    = (const float*)d_in[5];
    const float* Wv    = (const float*)d_in[6];
    const float* Wo    = (const float*)d_in[7];
    const float* bo    = (const float*)d_in[8];
    float* out = (float*)d_out;

    char* ws = (char*)d_ws;
    bf16* Qws = (bf16*)(ws);                         // 8 MB [n,h,s,64]
    bf16* Kws = (bf16*)(ws + (8u  << 20));           // 8 MB [n,h,s,64]
    bf16* Vt  = (bf16*)(ws + (16u << 20));           // 8 MB [n,h,64,s]
    bf16* Xqb = (bf16*)(ws + (24u << 20));           // 8 MB; after qkv: o_part0
    bf16* Xkb = (bf16*)(ws + (32u << 20));           // 8 MB; after qkv: o_part1
    bf16* Xvb = (bf16*)(ws + (40u << 20));           // 8 MB; after qkv: Aws (merged)
    bf16* Wqb = (bf16*)(ws + (48u << 20));           // 2 MB; after qkv: l_part (512KB)
    bf16* Wkb = (bf16*)(ws + (50u << 20));           // 2 MB
    bf16* Wvb = (bf16*)(ws + (52u << 20));           // 2 MB
    bf16* Wob = (bf16*)(ws + (54u << 20));           // 2 MB (live until out_gemm)
    unsigned long long* mbits = (unsigned long long*)(ws + (56u << 20));  // 1 MB
    bf16*  Op0 = Xqb;
    bf16*  Op1 = Xkb;
    bf16*  Aws = Xvb;
    float* Lp  = (float*)Wqb;

    cvt_all_k<<<dim3(1024, 8), 256, 0, stream>>>(query, key, value, Wq, Wk, Wv, Wo, mask,
                                                 Xqb, Xkb, Xvb, Wqb, Wkb, Wvb, Wob, mbits);
    qkv_gemm<<<dim3(32, 8, 3), 256, 0, stream>>>(Xqb, Xkb, Xvb, Wqb, Wkb, Wvb, Qws, Kws, Vt);
    attn_k<<<1024, 256, 0, stream>>>(Qws, Kws, Vt, mbits, Op0, Op1, Lp);
    merge_k<<<2048, 256, 0, stream>>>(Op0, Op1, Lp, Aws);
    out_gemm<<<dim3(32, 8), 256, 0, stream>>>(Aws, Wob, bo, out);
}